// Round 7
// baseline (1220.881 us; speedup 1.0000x reference)
//
#include <hip/hip_runtime.h>

#define DD 512
#define BB 256
#define SS 128
#define MTOT (BB*SS)
#define GROUPS 8
#define WPG 32            // workgroups per m-group (each owns 16 d-columns)
#define NWG (GROUPS*WPG)  // 256
#define NTHR 256
#define SLOTS (SS+1)

typedef __bf16 bf16;
typedef float f32x4 __attribute__((ext_vector_type(4)));
typedef __bf16 bf16x8 __attribute__((ext_vector_type(8)));

__device__ __forceinline__ float sigm(float z){ return 1.f/(1.f+__expf(-z)); }
__device__ __forceinline__ unsigned short b2u(bf16 v){ union{bf16 b; unsigned short u;} x; x.b=v; return x.u; }

__global__ void k_zero(int* c, int n){ for (int i=threadIdx.x; i<n; i+=NTHR) c[i]=0; }

// Returning atomic swap at the shared coherence point (sc0=return old, sc1=device-coherent).
// vmcnt ack of the RETURN VALUE proves the swap executed at the shared point.
__device__ __forceinline__ unsigned coh_swap(unsigned* addr, unsigned val){
  unsigned old;
  asm volatile("global_atomic_swap %0, %1, %2, off sc0 sc1"
               : "=v"(old) : "v"(addr), "v"(val) : "memory");
  return old;
}

// LDS map (dynamic, 163840 B total):
//   [0, 98304)        weights: 6 mats x [16 d][512 k] bf16, row-swizzled
//   [98304, 131072)   Hs: [32][512] bf16 swizzled   (tail aliased: Hn pack tile)
//   [131072, 163840)  Xs: [32][512] bf16 swizzled   (aliased: f32 partial-exchange)
__launch_bounds__(NTHR, 1)
__global__ void k_main(const float* __restrict__ x, const float* __restrict__ h0,
                       const float* __restrict__ Wu, const float* __restrict__ Uu, const float* __restrict__ bu,
                       const float* __restrict__ Wr, const float* __restrict__ Ur, const float* __restrict__ br,
                       const float* __restrict__ Wh, const float* __restrict__ Uh, const float* __restrict__ bh,
                       bf16* hb0, bf16* hb1,
                       int* cnt, float* __restrict__ out, float* __restrict__ hlast){
  extern __shared__ char smem[];
  char*  Wl  = smem;
  char*  HsB = smem + 98304;
  char*  XsB = smem + 131072;
  float* Xch = (float*)(smem + 131072);
  bf16*  Hn  = (bf16*)(smem + 98304);       // 32x16 pack tile (aliases Hs; dead then)

  const int tid  = threadIdx.x;
  const int w    = tid>>6, lane = tid&63;
  const int grp  = blockIdx.x >> 5, widx = blockIdx.x & 31;
  const int m0   = grp*32, d0 = widx*16;
  int* const cbase = cnt + grp*SLOTS;

  // ---- prologue: load + transpose + convert weight slices into LDS ----
  {
    const float* srcs[6] = {Uu, Ur, Uh, Wu, Wr, Wh};
    int d = tid&15, kb = tid>>4;
    for (int M=0; M<6; M++){
      const float* S = srcs[M];
      char* row = Wl + (size_t)(M*16 + d)*1024;
      int swz = (d&7)<<4;
      #pragma unroll 4
      for (int i=0; i<32; i++){
        int k = kb + i*16;
        float v = S[(size_t)k*DD + d0 + d];
        *(bf16*)(row + ((k*2) ^ swz)) = (bf16)v;
      }
    }
  }
  // biases for this WG's d-slice
  const int dcol = d0 + (lane&15);
  const float bu_v = bu[dcol], br_v = br[dcol], bh_v = bh[dcol];
  // fp32 h state in registers (waves 0,1 only)
  float hp[4];
  if (w < 2){
    #pragma unroll
    for (int j=0;j<4;j++)
      hp[j] = h0[(size_t)(m0 + w*16 + (lane>>4)*4 + j)*DD + dcol];
  }
  // ---- init bf16 h shadow via returning swaps (one dword per thread) ----
  const int pm = tid>>3, pdc = tid&7;       // pack coords: row, dword-col
  unsigned* const packdst0 = (unsigned*)(hb0 + (size_t)(m0+pm)*DD + d0 + pdc*2);
  unsigned* const packdst1 = (unsigned*)(hb1 + (size_t)(m0+pm)*DD + d0 + pdc*2);
  {
    const float* src = h0 + (size_t)(m0+pm)*DD + d0 + pdc*2;
    unsigned pv = (unsigned)b2u((bf16)src[0]) | ((unsigned)b2u((bf16)src[1]) << 16);
    coh_swap(packdst0, pv);
    asm volatile("s_waitcnt vmcnt(0)" ::: "memory");
  }
  __syncthreads();
  if (tid==0){
    unsigned old;
    asm volatile("global_atomic_add %0, %1, %2, off sc0 sc1"
                 : "=v"(old) : "v"(cbase), "v"(1u) : "memory");
    unsigned v;
    do {
      __builtin_amdgcn_s_sleep(2);
      asm volatile("global_load_dword %0, %1, off sc0 sc1\n\ts_waitcnt vmcnt(0)"
                   : "=v"(v) : "v"(cbase) : "memory");
    } while (v < WPG);
  }
  __syncthreads();

  const int mf = w&1, half = w>>1;
  const int arow = mf*16 + (lane&15);
  const int aswz = (arow&7)<<4;
  const int dswz = ((lane&15)&7)<<4;
  char* const abase = (half? XsB : HsB) + (size_t)arow*1024;
  char* const b0 = Wl + (size_t)((half*3+0)*16 + (lane&15))*1024;
  char* const b1 = Wl + (size_t)((half*3+1)*16 + (lane&15))*1024;
  char* const b2 = Wl + (size_t)((half*3+2)*16 + (lane&15))*1024;
  const int coff = lane>>4;

  for (int st=0; st<SS; st++){
    bf16* hcur = (st&1)? hb1 : hb0;
    // ---- stage Hs (coherent bf16 h shadow) and Xs (cached fp32 x -> bf16) ----
    {
      int r = tid>>3, c8 = tid&7;
      int swz = (r&7)<<4;
      const bf16*  gh = hcur + (size_t)(m0+r)*DD + c8*64;
      const float* gx = x + ((size_t)(m0+r)*SS + st)*DD + c8*64;
      bf16x8 hv[8];
      float4 xv[16];
      #pragma unroll
      for (int j=0;j<8;j++)
        asm volatile("global_load_dwordx4 %0, %1, off sc0 sc1" : "=&v"(hv[j]) : "v"(gh + j*8));
      #pragma unroll
      for (int j=0;j<16;j++)
        asm volatile("global_load_dwordx4 %0, %1, off" : "=&v"(xv[j]) : "v"(gx + j*4));
      asm volatile("s_waitcnt vmcnt(0)" ::: "memory");
      __builtin_amdgcn_sched_barrier(0);
      char* lh = HsB + (size_t)r*1024;
      char* lx = XsB + (size_t)r*1024;
      #pragma unroll
      for (int j=0;j<8;j++)
        *(bf16x8*)(lh + (((c8*8+j)*16) ^ swz)) = hv[j];
      #pragma unroll
      for (int j=0;j<8;j++){
        float4 a = xv[2*j], b = xv[2*j+1];
        bf16x8 v;
        v[0]=(bf16)a.x; v[1]=(bf16)a.y; v[2]=(bf16)a.z; v[3]=(bf16)a.w;
        v[4]=(bf16)b.x; v[5]=(bf16)b.y; v[6]=(bf16)b.z; v[7]=(bf16)b.w;
        *(bf16x8*)(lx + (((c8*8+j)*16) ^ swz)) = v;
      }
    }
    __syncthreads();
    // ---- K-loop: waves 0,1 = h@U (u,r,huh); waves 2,3 = x@W (u,r,xwh) ----
    f32x4 acc0{}, acc1{}, acc2{};
    #pragma unroll
    for (int i=0;i<16;i++){
      int ac = (i*4 + coff)*16;
      bf16x8 av  = *(const bf16x8*)(abase + (ac ^ aswz));
      bf16x8 bv0 = *(const bf16x8*)(b0 + (ac ^ dswz));
      bf16x8 bv1 = *(const bf16x8*)(b1 + (ac ^ dswz));
      bf16x8 bv2 = *(const bf16x8*)(b2 + (ac ^ dswz));
      acc0 = __builtin_amdgcn_mfma_f32_16x16x32_bf16(av, bv0, acc0, 0,0,0);
      acc1 = __builtin_amdgcn_mfma_f32_16x16x32_bf16(av, bv1, acc1, 0,0,0);
      acc2 = __builtin_amdgcn_mfma_f32_16x16x32_bf16(av, bv2, acc2, 0,0,0);
    }
    __syncthreads();             // Hs/Xs reads done everywhere; safe to alias-write
    if (half){
      float* dst = Xch + (size_t)(mf*64 + lane)*12;
      *(f32x4*)(dst+0) = acc0; *(f32x4*)(dst+4) = acc1; *(f32x4*)(dst+8) = acc2;
    }
    __syncthreads();
    if (!half){
      const float* src = Xch + (size_t)(mf*64 + lane)*12;
      f32x4 p0 = *(const f32x4*)(src+0);
      f32x4 p1 = *(const f32x4*)(src+4);
      f32x4 p2 = *(const f32x4*)(src+8);
      int mlocal = mf*16 + (lane>>4)*4;
      #pragma unroll
      for (int j=0;j<4;j++){
        float u  = sigm(acc0[j] + p0[j] + bu_v);
        float r  = sigm(acc1[j] + p1[j] + br_v);
        float hh = tanhf(p2[j] + bh_v + r*acc2[j]);
        float hn = (1.f-u)*hp[j] + u*hh;
        hp[j] = hn;
        int m = m0 + mlocal + j;
        out[((size_t)m*SS + st)*DD + dcol] = hn;
        Hn[(mlocal+j)*16 + (lane&15)] = (bf16)hn;
        if (st == SS-1) hlast[(size_t)m*DD + dcol] = hn;
      }
    }
    __syncthreads();             // Hn complete
    // ---- publish h to next step's buffer via returning swaps ----
    if (st < SS-1){
      unsigned pv = (unsigned)b2u(Hn[pm*16 + pdc*2]) | ((unsigned)b2u(Hn[pm*16 + pdc*2 + 1]) << 16);
      coh_swap((st&1)? packdst0 : packdst1, pv);
      asm volatile("s_waitcnt vmcnt(0)" ::: "memory");
      __syncthreads();
      int* cp = cbase + st + 1;
      if (tid==0){
        unsigned old;
        asm volatile("global_atomic_add %0, %1, %2, off sc0 sc1"
                     : "=v"(old) : "v"(cp), "v"(1u) : "memory");
        unsigned v;
        do {
          __builtin_amdgcn_s_sleep(2);
          asm volatile("global_load_dword %0, %1, off sc0 sc1\n\ts_waitcnt vmcnt(0)"
                       : "=v"(v) : "v"(cp) : "memory");
        } while (v < WPG);
      }
      __syncthreads();
    }
  }
}

extern "C" void kernel_launch(void* const* d_in, const int* in_sizes, int n_in,
                              void* d_out, int out_size, void* d_ws, size_t ws_size,
                              hipStream_t stream){
  const float* x   = (const float*)d_in[0];
  // d_in[1] = item (unused: softmax over length-1 axis == 1)
  const float* h0  = (const float*)d_in[2];
  const float* Wu  = (const float*)d_in[3];
  const float* Uu  = (const float*)d_in[4];
  const float* bu  = (const float*)d_in[5];
  const float* Wr  = (const float*)d_in[6];
  const float* Ur  = (const float*)d_in[7];
  const float* br  = (const float*)d_in[8];
  const float* Wh  = (const float*)d_in[9];
  const float* Uh  = (const float*)d_in[10];
  const float* bh  = (const float*)d_in[11];
  // d_in[12] = Wa (unused)
  float* out   = (float*)d_out;
  float* hlast = out + (size_t)MTOT*DD;

  char* ws = (char*)d_ws;
  bf16* hb0 = (bf16*)(ws);             // 256x512 bf16 = 256 KB
  bf16* hb1 = (bf16*)(ws + 0x40000);   // 256 KB
  int*  cnt = (int*)(ws + 0x80000);    // 8*129 ints

  static bool attr_done = false;
  if (!attr_done){
    hipFuncSetAttribute((const void*)k_main,
                        hipFuncAttributeMaxDynamicSharedMemorySize, 163840);
    attr_done = true;
  }

  k_zero<<<dim3(1), dim3(NTHR), 0, stream>>>(cnt, GROUPS*SLOTS);
  k_main<<<dim3(NWG), dim3(NTHR), 163840, stream>>>(
      x, h0, Wu, Uu, bu, Wr, Ur, br, Wh, Uh, bh, hb0, hb1, cnt, out, hlast);
}

// Round 8
// 1183.915 us; speedup vs baseline: 1.0312x; 1.0312x over previous
//
#include <hip/hip_runtime.h>

#define DD 512
#define BB 256
#define SS 128
#define MTOT (BB*SS)
#define GROUPS 8
#define WPG 32            // workgroups per m-group (each owns 16 d-columns)
#define NWG (GROUPS*WPG)  // 256
#define NTHR 256
#define SLOTS (SS+1)

typedef __bf16 bf16;
typedef float f32x4 __attribute__((ext_vector_type(4)));
typedef __bf16 bf16x8 __attribute__((ext_vector_type(8)));

__device__ __forceinline__ float sigm(float z){ return 1.f/(1.f+__expf(-z)); }
__device__ __forceinline__ unsigned short b2u(bf16 v){ union{bf16 b; unsigned short u;} x; x.b=v; return x.u; }

__global__ void k_zero(int* c, int n){ for (int i=threadIdx.x; i<n; i+=NTHR) c[i]=0; }

// Returning atomic swap at the shared coherence point (sc0=return old, sc1=device-coherent).
// vmcnt ack of the RETURN VALUE proves the swap executed at the shared point. (R7-proven)
__device__ __forceinline__ unsigned coh_swap(unsigned* addr, unsigned val){
  unsigned old;
  asm volatile("global_atomic_swap %0, %1, %2, off sc0 sc1"
               : "=v"(old) : "v"(addr), "v"(val) : "memory");
  return old;
}

// LDS (dynamic 98304 B; >80KB forces 1 WG/CU):
//   [0, 32768)      Hs: [32][512] bf16 swizzled   (aliased: Hn pack tile)
//   [32768, 65536)  Xs: [32][512] bf16 swizzled   (aliased: f32 partial-exchange)
__launch_bounds__(NTHR, 1)
__global__ void k_main(const float* __restrict__ x, const float* __restrict__ h0,
                       const float* __restrict__ Wu, const float* __restrict__ Uu, const float* __restrict__ bu,
                       const float* __restrict__ Wr, const float* __restrict__ Ur, const float* __restrict__ br,
                       const float* __restrict__ Wh, const float* __restrict__ Uh, const float* __restrict__ bh,
                       bf16* hb0, bf16* hb1,
                       int* cnt, float* __restrict__ out, float* __restrict__ hlast){
  extern __shared__ char smem[];
  char*  HsB = smem;
  char*  XsB = smem + 32768;
  float* Xch = (float*)(smem + 32768);
  bf16*  Hn  = (bf16*)(smem);

  const int tid  = threadIdx.x;
  const int w    = tid>>6, lane = tid&63;
  const int grp  = blockIdx.x >> 5, widx = blockIdx.x & 31;
  const int m0   = grp*32, d0 = widx*16;
  int* const cbase = cnt + grp*SLOTS;
  const int mf = w&1, half = w>>1;

  // ---- prologue: B-fragments into registers (3 mats x 16 k-chunks = 192 VGPR) ----
  bf16x8 bfr[3][16];
  {
    const float* mats[3];
    if (half){ mats[0]=Wu; mats[1]=Wr; mats[2]=Wh; }
    else     { mats[0]=Uu; mats[1]=Ur; mats[2]=Uh; }
    const int col = d0 + (lane&15);
    const int kr0 = (lane>>4)*8;
    #pragma unroll
    for (int g=0; g<3; ++g){
      const float* M = mats[g] + col;
      #pragma unroll
      for (int kc=0; kc<16; ++kc){
        bf16x8 v;
        #pragma unroll
        for (int j=0;j<8;j++) v[j] = (bf16)M[(size_t)(kc*32 + kr0 + j)*DD];
        bfr[g][kc] = v;
      }
    }
  }
  // biases for this WG's d-slice
  const int dcol = d0 + (lane&15);
  const float bu_v = bu[dcol], br_v = br[dcol], bh_v = bh[dcol];
  // fp32 h state in registers (waves 0,1 only)
  float hp[4];
  if (w < 2){
    #pragma unroll
    for (int j=0;j<4;j++)
      hp[j] = h0[(size_t)(m0 + mf*16 + (lane>>4)*4 + j)*DD + dcol];
  }
  // ---- init bf16 h shadow via returning swaps (one dword per thread) ----
  const int pm = tid>>3, pdc = tid&7;
  unsigned* const packdst0 = (unsigned*)(hb0 + (size_t)(m0+pm)*DD + d0 + pdc*2);
  unsigned* const packdst1 = (unsigned*)(hb1 + (size_t)(m0+pm)*DD + d0 + pdc*2);
  {
    const float* src = h0 + (size_t)(m0+pm)*DD + d0 + pdc*2;
    unsigned pv = (unsigned)b2u((bf16)src[0]) | ((unsigned)b2u((bf16)src[1]) << 16);
    coh_swap(packdst0, pv);
    asm volatile("s_waitcnt vmcnt(0)" ::: "memory");
  }
  __syncthreads();
  if (tid==0){
    unsigned old;
    asm volatile("global_atomic_add %0, %1, %2, off sc0 sc1"
                 : "=v"(old) : "v"(cbase), "v"(1u) : "memory");
    unsigned v;
    do {
      __builtin_amdgcn_s_sleep(2);
      asm volatile("global_load_dword %0, %1, off sc0 sc1\n\ts_waitcnt vmcnt(0)"
                   : "=v"(v) : "v"(cbase) : "memory");
    } while (v < WPG);
  }
  __syncthreads();

  const int arow = mf*16 + (lane&15);
  const int aswz = (arow&7)<<4;
  char* const abase = (half? XsB : HsB) + (size_t)arow*1024;
  const int coff = lane>>4;

  for (int st=0; st<SS; st++){
    bf16* hcur = (st&1)? hb1 : hb0;
    // ---- stage Hs (coherent h shadow) and Xs (fp32 x -> bf16), 2 batches ----
    {
      int r = tid>>3, c8 = tid&7;
      int swz = (r&7)<<4;
      const bf16*  gh = hcur + (size_t)(m0+r)*DD + c8*64;
      const float* gx = x + ((size_t)(m0+r)*SS + st)*DD + c8*64;
      char* lh = HsB + (size_t)r*1024;
      char* lx = XsB + (size_t)r*1024;
      bf16x8 hv[8];
      float4 xv[8];
      #pragma unroll
      for (int j=0;j<8;j++)
        asm volatile("global_load_dwordx4 %0, %1, off sc0 sc1" : "=&v"(hv[j]) : "v"(gh + j*8));
      #pragma unroll
      for (int j=0;j<8;j++)
        asm volatile("global_load_dwordx4 %0, %1, off" : "=&v"(xv[j]) : "v"(gx + j*4));
      asm volatile("s_waitcnt vmcnt(0)" ::: "memory");
      __builtin_amdgcn_sched_barrier(0);
      #pragma unroll
      for (int j=0;j<8;j++)
        *(bf16x8*)(lh + (((c8*8+j)*16) ^ swz)) = hv[j];
      #pragma unroll
      for (int j=0;j<4;j++){
        float4 a = xv[2*j], b = xv[2*j+1];
        bf16x8 v;
        v[0]=(bf16)a.x; v[1]=(bf16)a.y; v[2]=(bf16)a.z; v[3]=(bf16)a.w;
        v[4]=(bf16)b.x; v[5]=(bf16)b.y; v[6]=(bf16)b.z; v[7]=(bf16)b.w;
        *(bf16x8*)(lx + (((c8*8+j)*16) ^ swz)) = v;
      }
      #pragma unroll
      for (int j=0;j<8;j++)
        asm volatile("global_load_dwordx4 %0, %1, off" : "=&v"(xv[j]) : "v"(gx + 32 + j*4));
      asm volatile("s_waitcnt vmcnt(0)" ::: "memory");
      __builtin_amdgcn_sched_barrier(0);
      #pragma unroll
      for (int j=0;j<4;j++){
        float4 a = xv[2*j], b = xv[2*j+1];
        bf16x8 v;
        v[0]=(bf16)a.x; v[1]=(bf16)a.y; v[2]=(bf16)a.z; v[3]=(bf16)a.w;
        v[4]=(bf16)b.x; v[5]=(bf16)b.y; v[6]=(bf16)b.z; v[7]=(bf16)b.w;
        *(bf16x8*)(lx + (((c8*8+4+j)*16) ^ swz)) = v;
      }
    }
    __syncthreads();
    // ---- K-loop: 1 A-read + 3 reg-B MFMAs per iter; waves 0,1=h@U, 2,3=x@W ----
    f32x4 acc0{}, acc1{}, acc2{};
    #pragma unroll
    for (int it=0; it<16; it++){
      int ac = it*64 + coff*16;
      bf16x8 av = *(const bf16x8*)(abase + (ac ^ aswz));
      acc0 = __builtin_amdgcn_mfma_f32_16x16x32_bf16(av, bfr[0][it], acc0, 0,0,0);
      acc1 = __builtin_amdgcn_mfma_f32_16x16x32_bf16(av, bfr[1][it], acc1, 0,0,0);
      acc2 = __builtin_amdgcn_mfma_f32_16x16x32_bf16(av, bfr[2][it], acc2, 0,0,0);
    }
    __syncthreads();             // Hs/Xs reads done everywhere; safe to alias-write
    if (half){
      float* dst = Xch + (size_t)(mf*64 + lane)*12;
      *(f32x4*)(dst+0) = acc0; *(f32x4*)(dst+4) = acc1; *(f32x4*)(dst+8) = acc2;
    }
    __syncthreads();
    if (!half){
      const float* src = Xch + (size_t)(mf*64 + lane)*12;
      f32x4 p0 = *(const f32x4*)(src+0);
      f32x4 p1 = *(const f32x4*)(src+4);
      f32x4 p2 = *(const f32x4*)(src+8);
      int mlocal = mf*16 + (lane>>4)*4;
      #pragma unroll
      for (int j=0;j<4;j++){
        float u  = sigm(acc0[j] + p0[j] + bu_v);
        float r  = sigm(acc1[j] + p1[j] + br_v);
        float hh = tanhf(p2[j] + bh_v + r*acc2[j]);
        float hn = (1.f-u)*hp[j] + u*hh;
        hp[j] = hn;
        int m = m0 + mlocal + j;
        out[((size_t)m*SS + st)*DD + dcol] = hn;
        Hn[(mlocal+j)*16 + (lane&15)] = (bf16)hn;
        if (st == SS-1) hlast[(size_t)m*DD + dcol] = hn;
      }
    }
    __syncthreads();             // Hn complete
    // ---- publish h to next step's buffer via returning swaps ----
    if (st < SS-1){
      unsigned pv = (unsigned)b2u(Hn[pm*16 + pdc*2]) | ((unsigned)b2u(Hn[pm*16 + pdc*2 + 1]) << 16);
      coh_swap((st&1)? packdst0 : packdst1, pv);
      asm volatile("s_waitcnt vmcnt(0)" ::: "memory");
      __syncthreads();
      int* cp = cbase + st + 1;
      if (tid==0){
        unsigned old;
        asm volatile("global_atomic_add %0, %1, %2, off sc0 sc1"
                     : "=v"(old) : "v"(cp), "v"(1u) : "memory");
        unsigned v;
        do {
          __builtin_amdgcn_s_sleep(2);
          asm volatile("global_load_dword %0, %1, off sc0 sc1\n\ts_waitcnt vmcnt(0)"
                       : "=v"(v) : "v"(cp) : "memory");
        } while (v < WPG);
      }
      __syncthreads();
    }
  }
}

extern "C" void kernel_launch(void* const* d_in, const int* in_sizes, int n_in,
                              void* d_out, int out_size, void* d_ws, size_t ws_size,
                              hipStream_t stream){
  const float* x   = (const float*)d_in[0];
  // d_in[1] = item (unused: softmax over length-1 axis == 1)
  const float* h0  = (const float*)d_in[2];
  const float* Wu  = (const float*)d_in[3];
  const float* Uu  = (const float*)d_in[4];
  const float* bu  = (const float*)d_in[5];
  const float* Wr  = (const float*)d_in[6];
  const float* Ur  = (const float*)d_in[7];
  const float* br  = (const float*)d_in[8];
  const float* Wh  = (const float*)d_in[9];
  const float* Uh  = (const float*)d_in[10];
  const float* bh  = (const float*)d_in[11];
  // d_in[12] = Wa (unused)
  float* out   = (float*)d_out;
  float* hlast = out + (size_t)MTOT*DD;

  char* ws = (char*)d_ws;
  bf16* hb0 = (bf16*)(ws);             // 256x512 bf16 = 256 KB
  bf16* hb1 = (bf16*)(ws + 0x40000);   // 256 KB
  int*  cnt = (int*)(ws + 0x80000);    // 8*129 ints

  static bool attr_done = false;
  if (!attr_done){
    hipFuncSetAttribute((const void*)k_main,
                        hipFuncAttributeMaxDynamicSharedMemorySize, 98304);
    attr_done = true;
  }

  k_zero<<<dim3(1), dim3(NTHR), 0, stream>>>(cnt, GROUPS*SLOTS);
  k_main<<<dim3(NWG), dim3(NTHR), 98304, stream>>>(
      x, h0, Wu, Uu, bu, Wr, Ur, br, Wh, Uh, bh, hb0, hb1, cnt, out, hlast);
}

// Round 9
// 1142.714 us; speedup vs baseline: 1.0684x; 1.0361x over previous
//
#include <hip/hip_runtime.h>

#define DD 512
#define BB 256
#define SS 128
#define MTOT (BB*SS)
#define GROUPS 8
#define WPG 32            // workgroups per m-group (each owns 16 d-columns)
#define NWG (GROUPS*WPG)  // 256
#define NTHR 256
#define SLOTS (SS+1)

typedef __bf16 bf16;
typedef float f32x4 __attribute__((ext_vector_type(4)));
typedef __bf16 bf16x8 __attribute__((ext_vector_type(8)));

__device__ __forceinline__ float sigm(float z){ return 1.f/(1.f+__expf(-z)); }
__device__ __forceinline__ unsigned short b2u(bf16 v){ union{bf16 b; unsigned short u;} x; x.b=v; return x.u; }

__global__ void k_zero(int* c, int n){ for (int i=threadIdx.x; i<n; i+=NTHR) c[i]=0; }

// ---- one-shot x fp32 -> bf16 (layout preserved) ----
__global__ __launch_bounds__(256) void k_cvtx(const float* __restrict__ X, bf16* __restrict__ Xb){
  size_t total = (size_t)MTOT*DD;
  for (size_t i = ((size_t)blockIdx.x*256 + threadIdx.x)*8; i < total; i += (size_t)gridDim.x*256*8){
    float4 a = *(const float4*)(X+i), b = *(const float4*)(X+i+4);
    bf16x8 v;
    v[0]=(bf16)a.x; v[1]=(bf16)a.y; v[2]=(bf16)a.z; v[3]=(bf16)a.w;
    v[4]=(bf16)b.x; v[5]=(bf16)b.y; v[6]=(bf16)b.z; v[7]=(bf16)b.w;
    *(bf16x8*)(Xb+i) = v;
  }
}

// Returning atomic swap at the shared coherence point (sc0=return old, sc1=device-coherent).
// vmcnt ack of the RETURN VALUE proves the swap executed at the shared point. (R7/R8-proven)
__device__ __forceinline__ unsigned coh_swap(unsigned* addr, unsigned val){
  unsigned old;
  asm volatile("global_atomic_swap %0, %1, %2, off sc0 sc1"
               : "=v"(old) : "v"(addr), "v"(val) : "memory");
  return old;
}

// LDS (dynamic 65536 B):
//   [0, 32768)      Hs: [32][512] bf16 swizzled   (aliased: Hn pack tile)
//   [32768, 65536)  Xs: [32][512] bf16 swizzled   (aliased: f32 partial-exchange)
__launch_bounds__(NTHR, 1)
__global__ void k_main(const bf16* __restrict__ xb, const float* __restrict__ h0,
                       const float* __restrict__ Wu, const float* __restrict__ Uu, const float* __restrict__ bu,
                       const float* __restrict__ Wr, const float* __restrict__ Ur, const float* __restrict__ br,
                       const float* __restrict__ Wh, const float* __restrict__ Uh, const float* __restrict__ bh,
                       bf16* hb0, bf16* hb1,
                       int* cnt, float* __restrict__ out, float* __restrict__ hlast){
  extern __shared__ char smem[];
  char*  HsB = smem;
  char*  XsB = smem + 32768;
  float* Xch = (float*)(smem + 32768);
  bf16*  Hn  = (bf16*)(smem);

  const int tid  = threadIdx.x;
  const int w    = tid>>6, lane = tid&63;
  // XCD-aware mapping: blocks g, g+8, g+16, ... round-robin to the same XCD,
  // so each m-group's 32 WGs co-reside on one XCD (x slice L2-shared). Perf-only.
  const int grp  = blockIdx.x & 7, widx = blockIdx.x >> 3;
  const int m0   = grp*32, d0 = widx*16;
  int* const cbase = cnt + grp*SLOTS;
  const int mf = w&1, half = w>>1;

  // ---- prologue: B-fragments into registers (3 mats x 16 k-chunks = 192 VGPR) ----
  bf16x8 bfr[3][16];
  {
    const float* mats[3];
    if (half){ mats[0]=Wu; mats[1]=Wr; mats[2]=Wh; }
    else     { mats[0]=Uu; mats[1]=Ur; mats[2]=Uh; }
    const int col = d0 + (lane&15);
    const int kr0 = (lane>>4)*8;
    #pragma unroll
    for (int g=0; g<3; ++g){
      const float* M = mats[g] + col;
      #pragma unroll
      for (int kc=0; kc<16; ++kc){
        bf16x8 v;
        #pragma unroll
        for (int j=0;j<8;j++) v[j] = (bf16)M[(size_t)(kc*32 + kr0 + j)*DD];
        bfr[g][kc] = v;
      }
    }
  }
  // biases for this WG's d-slice
  const int dcol = d0 + (lane&15);
  const float bu_v = bu[dcol], br_v = br[dcol], bh_v = bh[dcol];
  // fp32 h state in registers (waves 0,1 only)
  float hp[4];
  if (w < 2){
    #pragma unroll
    for (int j=0;j<4;j++)
      hp[j] = h0[(size_t)(m0 + mf*16 + (lane>>4)*4 + j)*DD + dcol];
  }
  // ---- init bf16 h shadow via returning swaps (one dword per thread) ----
  const int pm = tid>>3, pdc = tid&7;
  unsigned* const packdst0 = (unsigned*)(hb0 + (size_t)(m0+pm)*DD + d0 + pdc*2);
  unsigned* const packdst1 = (unsigned*)(hb1 + (size_t)(m0+pm)*DD + d0 + pdc*2);
  {
    const float* src = h0 + (size_t)(m0+pm)*DD + d0 + pdc*2;
    unsigned pv = (unsigned)b2u((bf16)src[0]) | ((unsigned)b2u((bf16)src[1]) << 16);
    coh_swap(packdst0, pv);
    asm volatile("s_waitcnt vmcnt(0)" ::: "memory");
  }
  __syncthreads();
  if (tid==0){
    unsigned old;
    asm volatile("global_atomic_add %0, %1, %2, off sc0 sc1"
                 : "=v"(old) : "v"(cbase), "v"(1u) : "memory");
    unsigned v;
    do {
      __builtin_amdgcn_s_sleep(2);
      asm volatile("global_load_dword %0, %1, off sc0 sc1\n\ts_waitcnt vmcnt(0)"
                   : "=v"(v) : "v"(cbase) : "memory");
    } while (v < WPG);
  }
  __syncthreads();

  const int arow = mf*16 + (lane&15);
  const int aswz = (arow&7)<<4;
  char* const abase = (half? XsB : HsB) + (size_t)arow*1024;
  const int coff = lane>>4;

  for (int st=0; st<SS; st++){
    bf16* hcur = (st&1)? hb1 : hb0;
    // ---- stage Hs (coherent h shadow) and Xs (bf16 x, L2-cached) ----
    {
      int r = tid>>3, c8 = tid&7;
      int swz = (r&7)<<4;
      const bf16* gh = hcur + (size_t)(m0+r)*DD + c8*64;
      const bf16* gx = xb + ((size_t)(m0+r)*SS + st)*DD + c8*64;
      char* lh = HsB + (size_t)r*1024;
      char* lx = XsB + (size_t)r*1024;
      bf16x8 hv[8], xv[8];
      #pragma unroll
      for (int j=0;j<8;j++)
        asm volatile("global_load_dwordx4 %0, %1, off sc0 sc1" : "=&v"(hv[j]) : "v"(gh + j*8));
      #pragma unroll
      for (int j=0;j<8;j++)
        asm volatile("global_load_dwordx4 %0, %1, off" : "=&v"(xv[j]) : "v"(gx + j*8));
      asm volatile("s_waitcnt vmcnt(0)" ::: "memory");
      __builtin_amdgcn_sched_barrier(0);
      #pragma unroll
      for (int j=0;j<8;j++)
        *(bf16x8*)(lh + (((c8*8+j)*16) ^ swz)) = hv[j];
      #pragma unroll
      for (int j=0;j<8;j++)
        *(bf16x8*)(lx + (((c8*8+j)*16) ^ swz)) = xv[j];
    }
    __syncthreads();
    // ---- K-loop: 1 A-read + 3 reg-B MFMAs per iter; waves 0,1=h@U, 2,3=x@W ----
    f32x4 acc0{}, acc1{}, acc2{};
    #pragma unroll
    for (int it=0; it<16; it++){
      int ac = it*64 + coff*16;
      bf16x8 av = *(const bf16x8*)(abase + (ac ^ aswz));
      acc0 = __builtin_amdgcn_mfma_f32_16x16x32_bf16(av, bfr[0][it], acc0, 0,0,0);
      acc1 = __builtin_amdgcn_mfma_f32_16x16x32_bf16(av, bfr[1][it], acc1, 0,0,0);
      acc2 = __builtin_amdgcn_mfma_f32_16x16x32_bf16(av, bfr[2][it], acc2, 0,0,0);
    }
    __syncthreads();             // Hs/Xs reads done everywhere; safe to alias-write
    if (half){
      float* dst = Xch + (size_t)(mf*64 + lane)*12;
      *(f32x4*)(dst+0) = acc0; *(f32x4*)(dst+4) = acc1; *(f32x4*)(dst+8) = acc2;
    }
    __syncthreads();
    if (!half){
      const float* src = Xch + (size_t)(mf*64 + lane)*12;
      f32x4 p0 = *(const f32x4*)(src+0);
      f32x4 p1 = *(const f32x4*)(src+4);
      f32x4 p2 = *(const f32x4*)(src+8);
      int mlocal = mf*16 + (lane>>4)*4;
      #pragma unroll
      for (int j=0;j<4;j++){
        float u  = sigm(acc0[j] + p0[j] + bu_v);
        float r  = sigm(acc1[j] + p1[j] + br_v);
        float hh = tanhf(p2[j] + bh_v + r*acc2[j]);
        float hn = (1.f-u)*hp[j] + u*hh;
        hp[j] = hn;
        int m = m0 + mlocal + j;
        out[((size_t)m*SS + st)*DD + dcol] = hn;
        Hn[(mlocal+j)*16 + (lane&15)] = (bf16)hn;
        if (st == SS-1) hlast[(size_t)m*DD + dcol] = hn;
      }
    }
    __syncthreads();             // Hn complete
    // ---- publish h to next step's buffer via returning swaps ----
    if (st < SS-1){
      unsigned pv = (unsigned)b2u(Hn[pm*16 + pdc*2]) | ((unsigned)b2u(Hn[pm*16 + pdc*2 + 1]) << 16);
      coh_swap((st&1)? packdst0 : packdst1, pv);
      asm volatile("s_waitcnt vmcnt(0)" ::: "memory");
      __syncthreads();
      int* cp = cbase + st + 1;
      if (tid==0){
        unsigned old;
        asm volatile("global_atomic_add %0, %1, %2, off sc0 sc1"
                     : "=v"(old) : "v"(cp), "v"(1u) : "memory");
        unsigned v;
        do {
          __builtin_amdgcn_s_sleep(2);
          asm volatile("global_load_dword %0, %1, off sc0 sc1\n\ts_waitcnt vmcnt(0)"
                       : "=v"(v) : "v"(cp) : "memory");
        } while (v < WPG);
      }
      __syncthreads();
    }
  }
}

extern "C" void kernel_launch(void* const* d_in, const int* in_sizes, int n_in,
                              void* d_out, int out_size, void* d_ws, size_t ws_size,
                              hipStream_t stream){
  const float* x   = (const float*)d_in[0];
  // d_in[1] = item (unused: softmax over length-1 axis == 1)
  const float* h0  = (const float*)d_in[2];
  const float* Wu  = (const float*)d_in[3];
  const float* Uu  = (const float*)d_in[4];
  const float* bu  = (const float*)d_in[5];
  const float* Wr  = (const float*)d_in[6];
  const float* Ur  = (const float*)d_in[7];
  const float* br  = (const float*)d_in[8];
  const float* Wh  = (const float*)d_in[9];
  const float* Uh  = (const float*)d_in[10];
  const float* bh  = (const float*)d_in[11];
  // d_in[12] = Wa (unused)
  float* out   = (float*)d_out;
  float* hlast = out + (size_t)MTOT*DD;

  char* ws = (char*)d_ws;
  bf16* xb  = (bf16*)(ws);               // 32768x512 bf16 = 32 MB
  bf16* hb0 = (bf16*)(ws + 0x2000000);   // 256 KB
  bf16* hb1 = (bf16*)(ws + 0x2040000);   // 256 KB
  int*  cnt = (int*)(ws + 0x2080000);    // 8*129 ints

  k_cvtx<<<dim3(2048), dim3(256), 0, stream>>>(x, xb);
  k_zero<<<dim3(1), dim3(NTHR), 0, stream>>>(cnt, GROUPS*SLOTS);
  k_main<<<dim3(NWG), dim3(NTHR), 65536, stream>>>(
      xb, h0, Wu, Uu, bu, Wr, Ur, br, Wh, Uh, bh, hb0, hb1, cnt, out, hlast);
}

// Round 12
// 879.361 us; speedup vs baseline: 1.3884x; 1.2995x over previous
//
#include <hip/hip_runtime.h>

#define DD 512
#define BB 256
#define SS 128
#define MTOT (BB*SS)
#define GROUPS 8
#define WPG 32
#define NWG (GROUPS*WPG)  // 256
#define NTHR 256
#define SLOTS (SS+1)

typedef __bf16 bf16;
typedef float f32x4 __attribute__((ext_vector_type(4)));
typedef __bf16 bf16x8 __attribute__((ext_vector_type(8)));

__device__ __forceinline__ float sigm(float z){ return 1.f/(1.f+__expf(-z)); }
__device__ __forceinline__ unsigned short b2u(bf16 v){ union{bf16 b; unsigned short u;} x; x.b=v; return x.u; }

__global__ void k_zero(int* c, int n){ for (int i=threadIdx.x; i<n; i+=NTHR) c[i]=0; }

// ---- one-shot x fp32 -> bf16 ----
__global__ __launch_bounds__(256) void k_cvtx(const float* __restrict__ X, bf16* __restrict__ Xb){
  size_t total = (size_t)MTOT*DD;
  for (size_t i = ((size_t)blockIdx.x*256 + threadIdx.x)*8; i < total; i += (size_t)gridDim.x*256*8){
    float4 a = *(const float4*)(X+i), b = *(const float4*)(X+i+4);
    bf16x8 v;
    v[0]=(bf16)a.x; v[1]=(bf16)a.y; v[2]=(bf16)a.z; v[3]=(bf16)a.w;
    v[4]=(bf16)b.x; v[5]=(bf16)b.y; v[6]=(bf16)b.z; v[7]=(bf16)b.w;
    *(bf16x8*)(Xb+i) = v;
  }
}

// Returning swap at the DEVICE coherence point (L3): vmcnt-ack of the returned
// value proves the data is physically at the shared point. R7/R8/R9-proven.
__device__ __forceinline__ void swapG(unsigned* a, unsigned v){
  unsigned old;
  asm volatile("global_atomic_swap %0, %1, %2, off sc0 sc1" : "=v"(old) : "v"(a), "v"(v) : "memory");
}

// LDS: [0,32768) Hs [32][512] bf16 swizzled (row0 aliased: Hn pack tile);
//      [32768,65536) Xs (aliased: f32 partial exchange)
__launch_bounds__(NTHR, 1)
__global__ void k_main(const bf16* __restrict__ xb, const float* __restrict__ h0,
                       const float* __restrict__ Wu, const float* __restrict__ Uu, const float* __restrict__ bu,
                       const float* __restrict__ Wr, const float* __restrict__ Ur, const float* __restrict__ br,
                       const float* __restrict__ Wh, const float* __restrict__ Uh, const float* __restrict__ bh,
                       bf16* hb0, bf16* hb1,
                       int* cnt, float* __restrict__ out, float* __restrict__ hlast){
  extern __shared__ char smem[];
  char*  HsB = smem;
  char*  XsB = smem + 32768;
  float* Xch = (float*)(smem + 32768);
  bf16*  Hn  = (bf16*)(smem);

  const int tid = threadIdx.x, w = tid>>6, lane = tid&63;
  const int grp = blockIdx.x & 7, widx = blockIdx.x >> 3;   // XCD-swizzle (perf-only)
  const int m0 = grp*32, d0 = widx*16;
  int* const cbase = cnt + grp*SLOTS;
  const int mf = w&1, half = w>>1;

  // ---- weights into registers: 3 mats x 16 k-chunks (R8/R9-proven) ----
  bf16x8 bfr[3][16];
  {
    const float* mats[3];
    if (half){ mats[0]=Wu; mats[1]=Wr; mats[2]=Wh; }
    else     { mats[0]=Uu; mats[1]=Ur; mats[2]=Uh; }
    const int col = d0 + (lane&15);
    const int kr0 = (lane>>4)*8;
    #pragma unroll
    for (int g=0; g<3; ++g){
      const float* M = mats[g] + col;
      #pragma unroll
      for (int kc=0; kc<16; ++kc){
        bf16x8 v;
        #pragma unroll
        for (int j=0;j<8;j++) v[j] = (bf16)M[(size_t)(kc*32 + kr0 + j)*DD];
        bfr[g][kc] = v;
      }
    }
  }
  const int dcol = d0 + (lane&15);
  const float bu_v = bu[dcol], br_v = br[dcol], bh_v = bh[dcol];
  float hp[4];
  if (w < 2){
    #pragma unroll
    for (int j=0;j<4;j++)
      hp[j] = h0[(size_t)(m0 + mf*16 + (lane>>4)*4 + j)*DD + dcol];
  }
  // ---- init h shadow via returning swaps ----
  const int pm = tid>>3, pdc = tid&7;
  unsigned* const packdst0 = (unsigned*)(hb0 + (size_t)(m0+pm)*DD + d0 + pdc*2);
  unsigned* const packdst1 = (unsigned*)(hb1 + (size_t)(m0+pm)*DD + d0 + pdc*2);
  {
    const float* src = h0 + (size_t)(m0+pm)*DD + d0 + pdc*2;
    unsigned pv = (unsigned)b2u((bf16)src[0]) | ((unsigned)b2u((bf16)src[1]) << 16);
    swapG(packdst0, pv);
    asm volatile("s_waitcnt vmcnt(0)" ::: "memory");
  }
  __syncthreads();
  if (tid==0){
    unsigned old, v;
    asm volatile("global_atomic_add %0, %1, %2, off sc0 sc1" : "=v"(old) : "v"(cbase), "v"(1u) : "memory");
    do { __builtin_amdgcn_s_sleep(2);
         asm volatile("global_load_dword %0, %1, off sc0 sc1\n\ts_waitcnt vmcnt(0)" : "=v"(v) : "v"(cbase) : "memory");
    } while (v < WPG);
  }
  __syncthreads();

  const int r = tid>>3, c8 = tid&7;
  const int swz = (r&7)<<4;
  char* const lh = HsB + (size_t)r*1024;
  char* const lx = XsB + (size_t)r*1024;
  const int arow = mf*16 + (lane&15);
  const int aswz = (arow&7)<<4;
  char* const abase = (half? XsB : HsB) + (size_t)arow*1024;
  const int coff = lane>>4;
  const bf16* const gxrow = xb + (size_t)(m0+r)*SS*DD + c8*64;

  // ---- prologue: stage x for st=0 into Xs ----
  {
    bf16x8 xv[8];
    #pragma unroll
    for (int j=0;j<8;j++)
      asm volatile("global_load_dwordx4 %0, %1, off" : "=&v"(xv[j]) : "v"(gxrow + j*8));
    asm volatile("s_waitcnt vmcnt(0)" ::: "memory");
    __builtin_amdgcn_sched_barrier(0);
    #pragma unroll
    for (int j=0;j<8;j++)
      *(bf16x8*)(lx + (((c8*8+j)*16) ^ swz)) = xv[j];
  }

  for (int st=0; st<SS; st++){
    bf16* hcur = (st&1)? hb1 : hb0;
    // ---- stage Hs (coherent h shadow; x already prefetched) ----
    {
      const bf16* gh = hcur + (size_t)(m0+r)*DD + c8*64;
      bf16x8 hv[8];
      #pragma unroll
      for (int j=0;j<8;j++)
        asm volatile("global_load_dwordx4 %0, %1, off sc0 sc1" : "=&v"(hv[j]) : "v"(gh + j*8));
      asm volatile("s_waitcnt vmcnt(0)" ::: "memory");
      __builtin_amdgcn_sched_barrier(0);
      #pragma unroll
      for (int j=0;j<8;j++)
        *(bf16x8*)(lh + (((c8*8+j)*16) ^ swz)) = hv[j];
    }
    __syncthreads();                                     // (1)
    // ---- K-loop: 1 A ds_read + 3 reg-B MFMAs per iter; waves 0,1=h@U, 2,3=x@W ----
    f32x4 acc0{}, acc1{}, acc2{};
    #pragma unroll
    for (int it=0; it<16; it++){
      int ac = it*64 + coff*16;
      bf16x8 av = *(const bf16x8*)(abase + (ac ^ aswz));
      acc0 = __builtin_amdgcn_mfma_f32_16x16x32_bf16(av, bfr[0][it], acc0, 0,0,0);
      acc1 = __builtin_amdgcn_mfma_f32_16x16x32_bf16(av, bfr[1][it], acc1, 0,0,0);
      acc2 = __builtin_amdgcn_mfma_f32_16x16x32_bf16(av, bfr[2][it], acc2, 0,0,0);
    }
    __syncthreads();                                     // (2)
    if (half){
      float* dst = Xch + (size_t)(mf*64 + lane)*12;
      *(f32x4*)(dst+0) = acc0; *(f32x4*)(dst+4) = acc1; *(f32x4*)(dst+8) = acc2;
    }
    __syncthreads();                                     // (3)
    f32x4 hnv{};
    if (!half){
      const float* src = Xch + (size_t)(mf*64 + lane)*12;
      f32x4 p0 = *(const f32x4*)(src+0);
      f32x4 p1 = *(const f32x4*)(src+4);
      f32x4 p2 = *(const f32x4*)(src+8);
      int mlocal = mf*16 + (lane>>4)*4;
      #pragma unroll
      for (int j=0;j<4;j++){
        float u  = sigm(acc0[j] + p0[j] + bu_v);
        float rr = sigm(acc1[j] + p1[j] + br_v);
        float hh = tanhf(p2[j] + bh_v + rr*acc2[j]);
        float hn = (1.f-u)*hp[j] + u*hh;
        hp[j] = hn;
        hnv[j] = hn;
        Hn[(mlocal+j)*16 + (lane&15)] = (bf16)hn;
      }
    }
    __syncthreads();                                     // (4) Hn ready; Xs dead
    if (st < SS-1){
      // ---- publish h via returning swaps (ack) ----
      unsigned pv = (unsigned)b2u(Hn[pm*16 + pdc*2]) | ((unsigned)b2u(Hn[pm*16 + pdc*2 + 1]) << 16);
      unsigned* pd = (st&1)? packdst0 : packdst1;
      swapG(pd, pv);
      asm volatile("s_waitcnt vmcnt(0)" ::: "memory");
      __syncthreads();                                   // (5) all publishes acked
      // ---- fire arrival (non-returning), prefetch x for st+1 under the spin ----
      if (tid==0)
        asm volatile("global_atomic_add %0, %1, off sc1" :: "v"(cbase + st + 1), "v"(1u) : "memory");
      {
        const bf16* gx = gxrow + (size_t)(st+1)*DD;
        bf16x8 xv[8];
        #pragma unroll
        for (int j=0;j<8;j++)
          asm volatile("global_load_dwordx4 %0, %1, off" : "=&v"(xv[j]) : "v"(gx + j*8));
        asm volatile("s_waitcnt vmcnt(0)" ::: "memory");
        __builtin_amdgcn_sched_barrier(0);
        #pragma unroll
        for (int j=0;j<8;j++)
          *(bf16x8*)(lx + (((c8*8+j)*16) ^ swz)) = xv[j];
      }
      if (tid==0){
        unsigned v;
        int* cp = cbase + st + 1;
        do { __builtin_amdgcn_s_sleep(2);
             asm volatile("global_load_dword %0, %1, off sc0 sc1\n\ts_waitcnt vmcnt(0)" : "=v"(v) : "v"(cp) : "memory");
        } while (v < WPG);
      }
      __syncthreads();                                   // (6) barrier done + Xs staged
    }
    // ---- deferred output stores (drain in the shadow of next h-stage) ----
    if (!half){
      int mlocal = mf*16 + (lane>>4)*4;
      #pragma unroll
      for (int j=0;j<4;j++){
        int m = m0 + mlocal + j;
        out[((size_t)m*SS + st)*DD + dcol] = hnv[j];
        if (st == SS-1) hlast[(size_t)m*DD + dcol] = hnv[j];
      }
    }
  }
}

extern "C" void kernel_launch(void* const* d_in, const int* in_sizes, int n_in,
                              void* d_out, int out_size, void* d_ws, size_t ws_size,
                              hipStream_t stream){
  const float* x   = (const float*)d_in[0];
  // d_in[1] = item (unused: softmax over length-1 axis == 1)
  const float* h0  = (const float*)d_in[2];
  const float* Wu  = (const float*)d_in[3];
  const float* Uu  = (const float*)d_in[4];
  const float* bu  = (const float*)d_in[5];
  const float* Wr  = (const float*)d_in[6];
  const float* Ur  = (const float*)d_in[7];
  const float* br  = (const float*)d_in[8];
  const float* Wh  = (const float*)d_in[9];
  const float* Uh  = (const float*)d_in[10];
  const float* bh  = (const float*)d_in[11];
  // d_in[12] = Wa (unused)
  float* out   = (float*)d_out;
  float* hlast = out + (size_t)MTOT*DD;

  char* ws = (char*)d_ws;
  bf16* xb  = (bf16*)(ws);                 // 32 MB
  bf16* hb0 = (bf16*)(ws + 0x2000000);     // 256 KB
  bf16* hb1 = (bf16*)(ws + 0x2040000);     // 256 KB
  int*  cnt = (int*)(ws + 0x2080000);      // 8*129 ints

  k_cvtx<<<dim3(2048), dim3(256), 0, stream>>>(x, xb);
  k_zero<<<dim3(1), dim3(NTHR), 0, stream>>>(cnt, GROUPS*SLOTS);
  k_main<<<dim3(NWG), dim3(NTHR), 65536, stream>>>(
      xb, h0, Wu, Uu, bu, Wr, Ur, br, Wh, Uh, bh, hb0, hb1, cnt, out, hlast);
}

// Round 13
// 545.155 us; speedup vs baseline: 2.2395x; 1.6130x over previous
//
#include <hip/hip_runtime.h>

#define DD 512
#define BB 256
#define SS 128
#define MTOT (BB*SS)
#define GROUPS 8
#define WPG 32
#define NWG (GROUPS*WPG)  // 256
#define NTHR 256
#define SLOTS (SS+1)

typedef __bf16 bf16;
typedef float f32x4 __attribute__((ext_vector_type(4)));
typedef __bf16 bf16x8 __attribute__((ext_vector_type(8)));

__device__ __forceinline__ float sigm(float z){ return 1.f/(1.f+__expf(-z)); }
__device__ __forceinline__ unsigned short b2u(bf16 v){ union{bf16 b; unsigned short u;} x; x.b=v; return x.u; }

__global__ void k_zero(int* c, int n){ for (int i=threadIdx.x; i<n; i+=NTHR) c[i]=0; }

// ---- one-shot x fp32 -> bf16 ----
__global__ __launch_bounds__(256) void k_cvtx(const float* __restrict__ X, bf16* __restrict__ Xb){
  size_t total = (size_t)MTOT*DD;
  for (size_t i = ((size_t)blockIdx.x*256 + threadIdx.x)*8; i < total; i += (size_t)gridDim.x*256*8){
    float4 a = *(const float4*)(X+i), b = *(const float4*)(X+i+4);
    bf16x8 v;
    v[0]=(bf16)a.x; v[1]=(bf16)a.y; v[2]=(bf16)a.z; v[3]=(bf16)a.w;
    v[4]=(bf16)b.x; v[5]=(bf16)b.y; v[6]=(bf16)b.z; v[7]=(bf16)b.w;
    *(bf16x8*)(Xb+i) = v;
  }
}

// Returning swap at the DEVICE coherence point (L3). R7-R12-proven.
__device__ __forceinline__ void swapG(unsigned* a, unsigned v){
  unsigned old;
  asm volatile("global_atomic_swap %0, %1, %2, off sc0 sc1" : "=v"(old) : "v"(a), "v"(v) : "memory");
}

// A-fragment loads: 16 x dwordx4 from one row, stride 64 B.
#define LDH(I,J) asm volatile("global_load_dwordx4 %0, %1, off offset:" #J " sc0 sc1" : "=&v"(av[I]) : "v"(g))
#define LDX(I,J) asm volatile("global_load_dwordx4 %0, %1, off offset:" #J : "=&v"(av[I]) : "v"(g))

// LDS (16384 B): [0,6144) Xch f32 exchange (stride-12 dwords, conflict-free);
//                [8192, 8192+1280) Hn pack tile [32][20] bf16 (stride-20, conflict-free)
__launch_bounds__(NTHR, 1)
__global__ void k_main(const bf16* __restrict__ xb, const float* __restrict__ h0,
                       const float* __restrict__ Wu, const float* __restrict__ Uu, const float* __restrict__ bu,
                       const float* __restrict__ Wr, const float* __restrict__ Ur, const float* __restrict__ br,
                       const float* __restrict__ Wh, const float* __restrict__ Uh, const float* __restrict__ bh,
                       bf16* hb0, bf16* hb1,
                       int* cnt, float* __restrict__ out, float* __restrict__ hlast){
  extern __shared__ char smem[];
  float* Xch = (float*)smem;
  bf16*  Hn  = (bf16*)(smem + 8192);

  const int tid = threadIdx.x, w = tid>>6, lane = tid&63;
  const int grp = blockIdx.x & 7, widx = blockIdx.x >> 3;   // XCD-swizzle (perf-only)
  const int m0 = grp*32, d0 = widx*16;
  int* const cbase = cnt + grp*SLOTS;
  const int mf = w&1, half = w>>1;

  // ---- weights into registers: 3 mats x 16 k-chunks (R8-R12-proven) ----
  bf16x8 bfr[3][16];
  {
    const float* mats[3];
    if (half){ mats[0]=Wu; mats[1]=Wr; mats[2]=Wh; }
    else     { mats[0]=Uu; mats[1]=Ur; mats[2]=Uh; }
    const int col = d0 + (lane&15);
    const int kr0 = (lane>>4)*8;
    #pragma unroll
    for (int g=0; g<3; ++g){
      const float* M = mats[g] + col;
      #pragma unroll
      for (int kc=0; kc<16; ++kc){
        bf16x8 v;
        #pragma unroll
        for (int j=0;j<8;j++) v[j] = (bf16)M[(size_t)(kc*32 + kr0 + j)*DD];
        bfr[g][kc] = v;
      }
    }
  }
  const int dcol = d0 + (lane&15);
  const float bu_v = bu[dcol], br_v = br[dcol], bh_v = bh[dcol];
  float hp[4];
  if (w < 2){
    #pragma unroll
    for (int j=0;j<4;j++)
      hp[j] = h0[(size_t)(m0 + mf*16 + (lane>>4)*4 + j)*DD + dcol];
  }
  // ---- init h shadow via returning swaps + slot-0 barrier (R7-R12-proven) ----
  const int pm = tid>>3, pdc = tid&7;
  unsigned* const packdst0 = (unsigned*)(hb0 + (size_t)(m0+pm)*DD + d0 + pdc*2);
  unsigned* const packdst1 = (unsigned*)(hb1 + (size_t)(m0+pm)*DD + d0 + pdc*2);
  {
    const float* src = h0 + (size_t)(m0+pm)*DD + d0 + pdc*2;
    unsigned pv = (unsigned)b2u((bf16)src[0]) | ((unsigned)b2u((bf16)src[1]) << 16);
    swapG(packdst0, pv);
    asm volatile("s_waitcnt vmcnt(0)" ::: "memory");
  }
  __syncthreads();
  if (tid==0){
    unsigned old, v;
    asm volatile("global_atomic_add %0, %1, %2, off sc0 sc1" : "=v"(old) : "v"(cbase), "v"(1u) : "memory");
    do { __builtin_amdgcn_s_sleep(2);
         asm volatile("global_load_dword %0, %1, off sc0 sc1\n\ts_waitcnt vmcnt(0)" : "=v"(v) : "v"(cbase) : "memory");
    } while (v < WPG);
  }
  __syncthreads();

  // per-lane A-source rows
  const int arow = mf*16 + (lane&15);
  const int coff = lane>>4;
  const bf16* const hA0 = hb0 + (size_t)(m0+arow)*DD + coff*8;
  const bf16* const hA1 = hb1 + (size_t)(m0+arow)*DD + coff*8;
  const bf16* const xA  = xb + (size_t)(m0+arow)*SS*DD + coff*8;

  bf16x8 av[16];
  if (half){   // pre-issue x A-frags for st=0
    const bf16* g = xA;
    LDX(0,0); LDX(1,64); LDX(2,128); LDX(3,192); LDX(4,256); LDX(5,320); LDX(6,384); LDX(7,448);
    LDX(8,512); LDX(9,576); LDX(10,640); LDX(11,704); LDX(12,768); LDX(13,832); LDX(14,896); LDX(15,960);
  }

  for (int st=0; st<SS; st++){
    if (!half){  // h A-frags (coherent)
      const bf16* g = (st&1)? hA1 : hA0;
      LDH(0,0); LDH(1,64); LDH(2,128); LDH(3,192); LDH(4,256); LDH(5,320); LDH(6,384); LDH(7,448);
      LDH(8,512); LDH(9,576); LDH(10,640); LDH(11,704); LDH(12,768); LDH(13,832); LDH(14,896); LDH(15,960);
    }
    asm volatile("s_waitcnt vmcnt(0)" ::: "memory");
    __builtin_amdgcn_sched_barrier(0);
    // ---- K-loop: pure-register, 48 MFMAs ----
    f32x4 acc0{}, acc1{}, acc2{};
    #pragma unroll
    for (int it=0; it<16; it++){
      acc0 = __builtin_amdgcn_mfma_f32_16x16x32_bf16(av[it], bfr[0][it], acc0, 0,0,0);
      acc1 = __builtin_amdgcn_mfma_f32_16x16x32_bf16(av[it], bfr[1][it], acc1, 0,0,0);
      acc2 = __builtin_amdgcn_mfma_f32_16x16x32_bf16(av[it], bfr[2][it], acc2, 0,0,0);
    }
    if (half){
      float* dst = Xch + (size_t)(mf*64 + lane)*12;
      *(f32x4*)(dst+0) = acc0; *(f32x4*)(dst+4) = acc1; *(f32x4*)(dst+8) = acc2;
    }
    __syncthreads();                                     // (3) Xch ready
    f32x4 hnv{};
    if (!half){
      const float* src = Xch + (size_t)(mf*64 + lane)*12;
      f32x4 p0 = *(const f32x4*)(src+0);
      f32x4 p1 = *(const f32x4*)(src+4);
      f32x4 p2 = *(const f32x4*)(src+8);
      int mlocal = mf*16 + (lane>>4)*4;
      #pragma unroll
      for (int j=0;j<4;j++){
        float u  = sigm(acc0[j] + p0[j] + bu_v);
        float rr = sigm(acc1[j] + p1[j] + br_v);
        float hh = tanhf(p2[j] + bh_v + rr*acc2[j]);
        float hn = (1.f-u)*hp[j] + u*hh;
        hp[j] = hn;
        hnv[j] = hn;
        Hn[(mlocal+j)*20 + (lane&15)] = (bf16)hn;
      }
    } else if (st < SS-1){   // prefetch next x A-frags during epilogue/sync window
      const bf16* g = xA + (size_t)(st+1)*DD;
      LDX(0,0); LDX(1,64); LDX(2,128); LDX(3,192); LDX(4,256); LDX(5,320); LDX(6,384); LDX(7,448);
      LDX(8,512); LDX(9,576); LDX(10,640); LDX(11,704); LDX(12,768); LDX(13,832); LDX(14,896); LDX(15,960);
    }
    __syncthreads();                                     // (4) Hn ready
    if (st < SS-1){
      // ---- publish h via returning swaps (ack), then group barrier ----
      unsigned pv = (unsigned)b2u(Hn[pm*20 + pdc*2]) | ((unsigned)b2u(Hn[pm*20 + pdc*2 + 1]) << 16);
      unsigned* pd = (st&1)? packdst0 : packdst1;
      swapG(pd, pv);
      asm volatile("s_waitcnt vmcnt(0)" ::: "memory");
      __syncthreads();                                   // (5) all publishes acked
      if (tid==0){
        unsigned v;
        int* cp = cbase + st + 1;
        asm volatile("global_atomic_add %0, %1, off sc1" :: "v"(cp), "v"(1u) : "memory");
        do { __builtin_amdgcn_s_sleep(2);
             asm volatile("global_load_dword %0, %1, off sc0 sc1\n\ts_waitcnt vmcnt(0)" : "=v"(v) : "v"(cp) : "memory");
        } while (v < WPG);
      }
      __syncthreads();                                   // (6) barrier done
    }
    // ---- deferred output stores (drain under next step's A-load wait) ----
    if (!half){
      int mlocal = mf*16 + (lane>>4)*4;
      #pragma unroll
      for (int j=0;j<4;j++){
        int m = m0 + mlocal + j;
        out[((size_t)m*SS + st)*DD + dcol] = hnv[j];
        if (st == SS-1) hlast[(size_t)m*DD + dcol] = hnv[j];
      }
    }
  }
}

extern "C" void kernel_launch(void* const* d_in, const int* in_sizes, int n_in,
                              void* d_out, int out_size, void* d_ws, size_t ws_size,
                              hipStream_t stream){
  const float* x   = (const float*)d_in[0];
  // d_in[1] = item (unused: softmax over length-1 axis == 1)
  const float* h0  = (const float*)d_in[2];
  const float* Wu  = (const float*)d_in[3];
  const float* Uu  = (const float*)d_in[4];
  const float* bu  = (const float*)d_in[5];
  const float* Wr  = (const float*)d_in[6];
  const float* Ur  = (const float*)d_in[7];
  const float* br  = (const float*)d_in[8];
  const float* Wh  = (const float*)d_in[9];
  const float* Uh  = (const float*)d_in[10];
  const float* bh  = (const float*)d_in[11];
  // d_in[12] = Wa (unused)
  float* out   = (float*)d_out;
  float* hlast = out + (size_t)MTOT*DD;

  char* ws = (char*)d_ws;
  bf16* xb  = (bf16*)(ws);                 // 32 MB
  bf16* hb0 = (bf16*)(ws + 0x2000000);     // 256 KB
  bf16* hb1 = (bf16*)(ws + 0x2040000);     // 256 KB
  int*  cnt = (int*)(ws + 0x2080000);      // 8*129 ints

  k_cvtx<<<dim3(2048), dim3(256), 0, stream>>>(x, xb);
  k_zero<<<dim3(1), dim3(NTHR), 0, stream>>>(cnt, GROUPS*SLOTS);
  k_main<<<dim3(NWG), dim3(NTHR), 16384, stream>>>(
      xb, h0, Wu, Uu, bu, Wr, Ur, br, Wh, Uh, bh, hb0, hb1, cnt, out, hlast);
}